// Round 3
// baseline (69.900 us; speedup 1.0000x reference)
//
#include <hip/hip_runtime.h>
#include <math.h>
#include <stdint.h>

// D3PM absorbing q_sample, bit-exact vs JAX with threefry PARTITIONABLE mode
// (default since JAX 0.4.30):
//   split(key):       key_j   = (out0, out1) of threefry(k, hi=0, lo=j)
//   random_bits u32:  bits[i] = out0 ^ out1 of threefry(k, hi32(i), lo32(i))
//                     (the XOR fold is _threefry_random_bits_partitionable's
//                      bit_width<=32 path — round-1's out0-only was wrong)
//
// Argmax reduction: f32 gumbel is bounded in [-4.4697, 16.6355]; floor logit
// log(1e-10) = -23.026 puts every non-{x0,mask} entry <= -6.390, while the
// best of {x0,mask} is >= -4.4697 + log(max(a,1-a)+eps) >= -5.163. So only
// the x0 and mask entries can win -> 2 hashes per token instead of N.
//
// Shapes: B=256, L=1024, NS=516 (mask=3), NQ=33 (mask=32).
// Output (int32 flat): noised_structure (B*L), noised_sequence (B*L), t (B).

#define B_CONST 256
#define L_CONST 1024
#define NS_CONST 516
#define NQ_CONST 33
#define MASK_S 3
#define MASK_Q 32
#define ROWS (B_CONST * L_CONST)   /* 262144 */

// ---------------- threefry2x32 (exact JAX schedule) ----------------
__host__ __device__ inline void tf_round(uint32_t& x0, uint32_t& x1, int r) {
  x0 += x1;
  x1 = (x1 << r) | (x1 >> (32 - r));
  x1 ^= x0;
}

__host__ __device__ inline void threefry2x32(uint32_t k0, uint32_t k1,
                                             uint32_t x0, uint32_t x1,
                                             uint32_t& o0, uint32_t& o1) {
  const uint32_t ks2 = k0 ^ k1 ^ 0x1BD11BDAu;
  x0 += k0; x1 += k1;
  tf_round(x0, x1, 13); tf_round(x0, x1, 15); tf_round(x0, x1, 26); tf_round(x0, x1, 6);
  x0 += k1; x1 += ks2 + 1u;
  tf_round(x0, x1, 17); tf_round(x0, x1, 29); tf_round(x0, x1, 16); tf_round(x0, x1, 24);
  x0 += ks2; x1 += k0 + 2u;
  tf_round(x0, x1, 13); tf_round(x0, x1, 15); tf_round(x0, x1, 26); tf_round(x0, x1, 6);
  x0 += k0; x1 += k1 + 3u;
  tf_round(x0, x1, 17); tf_round(x0, x1, 29); tf_round(x0, x1, 16); tf_round(x0, x1, 24);
  x0 += k1; x1 += ks2 + 4u;
  tf_round(x0, x1, 13); tf_round(x0, x1, 15); tf_round(x0, x1, 26); tf_round(x0, x1, 6);
  x0 += ks2; x1 += k0 + 5u;
  o0 = x0; o1 = x1;
}

// ---------------- JAX uniform -> gumbel, bit-faithful ----------------
__device__ inline float gumbel_from_bits(uint32_t bits) {
  const float tiny = 1.1754943508222875e-38f;  // jnp.finfo(f32).tiny
  // floats = bitcast((bits>>9)|0x3f800000) - 1  in [0, 1-2^-24]
  float f = __uint_as_float((bits >> 9) | 0x3f800000u) - 1.0f;
  // u = max(tiny, floats*(1-tiny)+tiny); (1-tiny)==1.0f in f32
  float u = fmaxf(tiny, f + tiny);
  float nl = -(float)log((double)u);     // correctly-rounded f32 log
  return -(float)log((double)nl);
}

__device__ inline float log_cr(float x) { return (float)log((double)x); }

__device__ inline int sample_row(uint32_t k0, uint32_t k1, uint32_t row,
                                 int N, int M, int x, float a) {
  if (x == M) return M;  // mask logit ~log(1) dominates; floors can't win
  const float EPSf = 1e-10f;
  const float lx = log_cr(a + EPSf);
  const float lm = log_cr((1.0f - a) + EPSf);
  const uint32_t base = row * (uint32_t)N;
  uint32_t ox0, ox1, om0, om1;
  threefry2x32(k0, k1, 0u, base + (uint32_t)x, ox0, ox1);
  threefry2x32(k0, k1, 0u, base + (uint32_t)M, om0, om1);
  // partitionable 32-bit fold: bits = out0 ^ out1
  const float vx = gumbel_from_bits(ox0 ^ ox1) + lx;
  const float vm = gumbel_from_bits(om0 ^ om1) + lm;
  // jnp.argmax first-occurrence tie-break: smaller index wins ties
  if (x < M) return (vx >= vm) ? x : M;
  return (vm >= vx) ? M : x;
}

__global__ __launch_bounds__(256)
void d3pm_kernel(const int* __restrict__ structure,
                 const int* __restrict__ sequence,
                 const int* __restrict__ tv,
                 const float* __restrict__ alpha,
                 int* __restrict__ out,
                 uint32_t ks0, uint32_t ks1, uint32_t kq0, uint32_t kq1) {
  const int gid = blockIdx.x * 256 + threadIdx.x;
  if (gid < ROWS) {
    const int b = gid >> 10;                  // L = 1024
    const float a = alpha[tv[b]];
    out[gid] = sample_row(ks0, ks1, (uint32_t)gid, NS_CONST, MASK_S,
                          structure[gid], a);
  } else if (gid < 2 * ROWS) {
    const int r = gid - ROWS;
    const int b = r >> 10;
    const float a = alpha[tv[b]];
    out[gid] = sample_row(kq0, kq1, (uint32_t)r, NQ_CONST, MASK_Q,
                          sequence[r], a);
  } else if (gid < 2 * ROWS + B_CONST) {
    out[gid] = tv[gid - 2 * ROWS];            // t passthrough
  }
}

extern "C" void kernel_launch(void* const* d_in, const int* in_sizes, int n_in,
                              void* d_out, int out_size, void* d_ws, size_t ws_size,
                              hipStream_t stream) {
  (void)in_sizes; (void)n_in; (void)out_size; (void)d_ws; (void)ws_size;
  const int*   structure = (const int*)d_in[0];
  const int*   sequence  = (const int*)d_in[1];
  const int*   t         = (const int*)d_in[2];
  const float* alpha     = (const float*)d_in[3];
  int* out = (int*)d_out;

  // Partitionable (foldlike) split of key(42) = (0, 42):
  //   ks = (out0, out1) of h(hi=0, lo=0); kq = (out0, out1) of h(hi=0, lo=1)
  uint32_t ks0, ks1, kq0, kq1;
  threefry2x32(0u, 42u, 0u, 0u, ks0, ks1);
  threefry2x32(0u, 42u, 0u, 1u, kq0, kq1);

  const int total = 2 * ROWS + B_CONST;  // 524544 = 2049 * 256
  d3pm_kernel<<<(total + 255) / 256, 256, 0, stream>>>(
      structure, sequence, t, alpha, out, ks0, ks1, kq0, kq1);
}

// Round 4
// 67.935 us; speedup vs baseline: 1.0289x; 1.0289x over previous
//
#include <hip/hip_runtime.h>
#include <math.h>
#include <stdint.h>

// D3PM absorbing q_sample, bit-exact vs JAX threefry PARTITIONABLE mode.
//   split(key):       key_j   = (out0, out1) of threefry(k, hi=0, lo=j)
//   random_bits u32:  bits[i] = out0 ^ out1 of threefry(k, hi32(i), lo32(i))
//
// Only {x0, mask} can win the argmax (floor logit log(1e-10) = -23.03 puts
// all other entries <= -6.39 < min winner -5.17). Per token: 2 threefry
// hashes + a 2-candidate compare.
//
// Perf structure (R4): fast f32 gumbel (log1pf for u>=0.5 avoids near-1
// cancellation; abs err <= ~2e-5) decides when |delta| > 2.5e-4; else exact
// f64-log fallback identical to the verified R3 path. 4 tokens/thread int4.
//
// Shapes: B=256, L=1024, NS=516 (mask=3), NQ=33 (mask=32).
// Output (int32 flat): noised_structure (B*L), noised_sequence (B*L), t (B).

#define B_CONST 256
#define L_CONST 1024
#define NS_CONST 516
#define NQ_CONST 33
#define MASK_S 3
#define MASK_Q 32
#define ROWS (B_CONST * L_CONST)   /* 262144 */
#define QUADS (ROWS / 4)           /* 65536 tokens-quads per stream */
#define QUADS_T (B_CONST / 4)      /* 64 */
#define TOTAL_THREADS (2 * QUADS + QUADS_T) /* 131136 */

// ---------------- threefry2x32 (exact JAX schedule) ----------------
__host__ __device__ inline void tf_round(uint32_t& x0, uint32_t& x1, int r) {
  x0 += x1;
  x1 = (x1 << r) | (x1 >> (32 - r));
  x1 ^= x0;
}

__host__ __device__ inline void threefry2x32(uint32_t k0, uint32_t k1,
                                             uint32_t x0, uint32_t x1,
                                             uint32_t& o0, uint32_t& o1) {
  const uint32_t ks2 = k0 ^ k1 ^ 0x1BD11BDAu;
  x0 += k0; x1 += k1;
  tf_round(x0, x1, 13); tf_round(x0, x1, 15); tf_round(x0, x1, 26); tf_round(x0, x1, 6);
  x0 += k1; x1 += ks2 + 1u;
  tf_round(x0, x1, 17); tf_round(x0, x1, 29); tf_round(x0, x1, 16); tf_round(x0, x1, 24);
  x0 += ks2; x1 += k0 + 2u;
  tf_round(x0, x1, 13); tf_round(x0, x1, 15); tf_round(x0, x1, 26); tf_round(x0, x1, 6);
  x0 += k0; x1 += k1 + 3u;
  tf_round(x0, x1, 17); tf_round(x0, x1, 29); tf_round(x0, x1, 16); tf_round(x0, x1, 24);
  x0 += k1; x1 += ks2 + 4u;
  tf_round(x0, x1, 13); tf_round(x0, x1, 15); tf_round(x0, x1, 26); tf_round(x0, x1, 6);
  x0 += ks2; x1 += k0 + 5u;
  o0 = x0; o1 = x1;
}

// ---------------- gumbel paths ----------------
// Exact (reference-faithful): each log correctly rounded to f32 via f64.
__device__ inline float gumbel_exact(uint32_t bits) {
  const float tiny = 1.1754943508222875e-38f;  // jnp.finfo(f32).tiny
  float f = __uint_as_float((bits >> 9) | 0x3f800000u) - 1.0f;
  float u = fmaxf(tiny, f + tiny);
  float nl = -(float)log((double)u);
  return -(float)log((double)nl);
}

// Fast f32: |g_fast - g_exact| <= ~2e-5 absolute.
//  - u = f (exact; f+tiny rounds to f for f>0, u=tiny for f=0)
//  - u>=0.5: nl = -log1p(u-1), u-1 Sterbenz-exact -> no near-1 blowup
//  - outer -logf(nl): abs err = rel-err(nl) + logf's own ~1e-6
__device__ inline float gumbel_fast(uint32_t bits) {
  const float tiny = 1.1754943508222875e-38f;
  float f = __uint_as_float((bits >> 9) | 0x3f800000u) - 1.0f;
  float u = fmaxf(tiny, f + tiny);
  float nl = (u >= 0.5f) ? -log1pf(u - 1.0f) : -__logf(u);
  return -__logf(nl);
}

__device__ inline float log_cr(float x) { return (float)log((double)x); }

// Decide one token. lx/lm are the exact f32 logits (same values the exact
// path uses). AMB = 2.5e-4 >> 2x fast-path error bound.
template <int N, int M>
__device__ inline int decide(uint32_t k0, uint32_t k1, uint32_t row,
                             int x, float lx, float lm) {
  if (x == M) return M;  // probs: a at mask + (1-a) at mask -> mask certain
  const uint32_t base = row * (uint32_t)N;
  uint32_t ox0, ox1, om0, om1;
  threefry2x32(k0, k1, 0u, base + (uint32_t)x, ox0, ox1);
  threefry2x32(k0, k1, 0u, base + (uint32_t)M, om0, om1);
  const uint32_t bx = ox0 ^ ox1, bm = om0 ^ om1;  // partitionable 32b fold
  float d = (gumbel_fast(bx) + lx) - (gumbel_fast(bm) + lm);
  if (fabsf(d) <= 2.5e-4f) {
    float vx = gumbel_exact(bx) + lx;
    float vm = gumbel_exact(bm) + lm;
    // jnp.argmax first-occurrence tie-break
    if (x < M) return (vx >= vm) ? x : M;
    return (vm >= vx) ? M : x;
  }
  return (d > 0.0f) ? x : M;
}

__global__ __launch_bounds__(256)
void d3pm_kernel(const int4* __restrict__ structure4,
                 const int4* __restrict__ sequence4,
                 const int* __restrict__ tv,
                 const float* __restrict__ alpha,
                 int4* __restrict__ out4,
                 uint32_t ks0, uint32_t ks1, uint32_t kq0, uint32_t kq1) {
  const int tid = blockIdx.x * 256 + threadIdx.x;
  const float EPSf = 1e-10f;

  if (tid < QUADS) {                       // structure: rows 4q..4q+3, same b
    const int q = tid;
    const int b = q >> 8;                  // (4q) >> 10
    const float a = alpha[tv[b]];
    const float lx = log_cr(a + EPSf);
    const float lm = log_cr((1.0f - a) + EPSf);
    const uint32_t r0 = (uint32_t)(4 * q);
    int4 xs = structure4[q];
    int4 o;
    o.x = decide<NS_CONST, MASK_S>(ks0, ks1, r0 + 0u, xs.x, lx, lm);
    o.y = decide<NS_CONST, MASK_S>(ks0, ks1, r0 + 1u, xs.y, lx, lm);
    o.z = decide<NS_CONST, MASK_S>(ks0, ks1, r0 + 2u, xs.z, lx, lm);
    o.w = decide<NS_CONST, MASK_S>(ks0, ks1, r0 + 3u, xs.w, lx, lm);
    out4[q] = o;
  } else if (tid < 2 * QUADS) {            // sequence
    const int q = tid - QUADS;
    const int b = q >> 8;
    const float a = alpha[tv[b]];
    const float lx = log_cr(a + EPSf);
    const float lm = log_cr((1.0f - a) + EPSf);
    const uint32_t r0 = (uint32_t)(4 * q);
    int4 xs = sequence4[q];
    int4 o;
    o.x = decide<NQ_CONST, MASK_Q>(kq0, kq1, r0 + 0u, xs.x, lx, lm);
    o.y = decide<NQ_CONST, MASK_Q>(kq0, kq1, r0 + 1u, xs.y, lx, lm);
    o.z = decide<NQ_CONST, MASK_Q>(kq0, kq1, r0 + 2u, xs.z, lx, lm);
    o.w = decide<NQ_CONST, MASK_Q>(kq0, kq1, r0 + 3u, xs.w, lx, lm);
    out4[QUADS + q] = o;
  } else if (tid < TOTAL_THREADS) {        // t passthrough
    const int q = tid - 2 * QUADS;
    out4[2 * QUADS + q] = ((const int4*)tv)[q];
  }
}

extern "C" void kernel_launch(void* const* d_in, const int* in_sizes, int n_in,
                              void* d_out, int out_size, void* d_ws, size_t ws_size,
                              hipStream_t stream) {
  (void)in_sizes; (void)n_in; (void)out_size; (void)d_ws; (void)ws_size;
  const int*   structure = (const int*)d_in[0];
  const int*   sequence  = (const int*)d_in[1];
  const int*   t         = (const int*)d_in[2];
  const float* alpha     = (const float*)d_in[3];

  // Partitionable (foldlike) split of key(42) = (0, 42):
  uint32_t ks0, ks1, kq0, kq1;
  threefry2x32(0u, 42u, 0u, 0u, ks0, ks1);
  threefry2x32(0u, 42u, 0u, 1u, kq0, kq1);

  d3pm_kernel<<<(TOTAL_THREADS + 255) / 256, 256, 0, stream>>>(
      (const int4*)structure, (const int4*)sequence, t, alpha,
      (int4*)d_out, ks0, ks1, kq0, kq1);
}